// Round 9
// baseline (138.496 us; speedup 1.0000x reference)
//
#include <hip/hip_runtime.h>

#define BB 8
#define NN 4096
#define MMK 1024
#define SMAX 2.0f
#define SCL 0.0883883476483184f   // 1/sqrt(128)

typedef __bf16 v8bf __attribute__((ext_vector_type(8)));
typedef float v4f __attribute__((ext_vector_type(4)));
#define MFMA16 __builtin_amdgcn_mfma_f32_16x16x32_bf16
#define MFMA16F8 __builtin_amdgcn_mfma_f32_16x16x32_fp8_fp8

static __device__ __forceinline__ unsigned pk4(float a, float b, float c, float d) {
    int u = __builtin_amdgcn_cvt_pk_fp8_f32(a, b, 0, false);
    u = __builtin_amdgcn_cvt_pk_fp8_f32(c, d, u, true);
    return (unsigned)u;
}
static __device__ __forceinline__ long long mk64(unsigned lo, unsigned hi) {
    return (long long)(((unsigned long long)hi << 32) | lo);
}
static __device__ __forceinline__ long long lo64(uint4 u) { return mk64(u.x, u.y); }
static __device__ __forceinline__ long long hi64(uint4 u) { return mk64(u.z, u.w); }

// ---- 16x16x32 fp8 fragment layouts (lane = quad*16 + l15) ----
// A/B token-frag: lane byte j of lo64 = T[tok=l15][c = 2p*32 + quad*8 + j]
//                 (hi64: c-slice 2p+1); 1KB chunk per (pair p).
// Q chunk idx  = (b*256 + qt)*2 + p
// K chunk idx  = ((b*32 + kchunk)*4 + grp*2 + p)       (grp = 16-key group)
// Vt chunk idx = ((b*32 + kchunk)*4 + cp); lane byte j of lo64 =
//                Vt[ch=cp*32+l15][k=kchunk*32+quad*8+j], hi64: ch+16.
// D-layout (16x16): row = quad*4 + reg, col = l15.

// ---------------- Kernel 1: projections via bf16 MFMA, fp8 frag-order out ----
#define XTS 68
__global__ __launch_bounds__(256, 1) void proj(
    const float* __restrict__ x, const float* __restrict__ y,
    const float* __restrict__ Wq, const float* __restrict__ bq,
    const float* __restrict__ Wk, const float* __restrict__ bk,
    const float* __restrict__ Wv, const float* __restrict__ bv,
    unsigned char* __restrict__ Qfr, unsigned char* __restrict__ Kfr,
    unsigned char* __restrict__ Vfr)
{
    __shared__ __align__(16) __bf16 xt[128 * XTS];
    __shared__ float bsh[128];

    const int tid = threadIdx.x;
    const int wave = tid >> 6, lane = tid & 63, l15 = lane & 15, quad = lane >> 4;
    const int bid = blockIdx.x;

    int job, b, t0, stride;
    const float *in, *W, *bias;
    if (bid < 512)      { job = 0; b = bid >> 6;         t0 = (bid & 63) * 64;         in = x; stride = NN;  W = Wq; bias = bq; }
    else if (bid < 640) { job = 1; b = (bid - 512) >> 4; t0 = ((bid - 512) & 15) * 64; in = y; stride = MMK; W = Wk; bias = bk; }
    else                { job = 2; b = (bid - 640) >> 4; t0 = ((bid - 640) & 15) * 64; in = y; stride = MMK; W = Wv; bias = bv; }

    #pragma unroll
    for (int i = 0; i < 8; ++i) {
        const int s = i * 256 + tid;
        const int c = s >> 4, c4 = s & 15;
        float4 v = *(const float4*)(in + (size_t)(b * 128 + c) * stride + t0 + c4 * 4);
        union { __bf16 h[4]; uint2 u; } o;
        o.h[0] = (__bf16)v.x; o.h[1] = (__bf16)v.y; o.h[2] = (__bf16)v.z; o.h[3] = (__bf16)v.w;
        *(uint2*)(xt + c * XTS + c4 * 4) = o.u;
    }
    if (tid < 128) bsh[tid] = bias[tid];
    __syncthreads();

    v8bf xf[4];
    {
        const int tok = wave * 16 + l15;
        #pragma unroll
        for (int cg = 0; cg < 4; ++cg) {
            union { __bf16 h[8]; v8bf v; } u;
            #pragma unroll
            for (int jj = 0; jj < 8; ++jj)
                u.h[jj] = xt[(cg * 32 + quad * 8 + jj) * XTS + tok];
            xf[cg] = u.v;
        }
    }

    for (int dg = 0; dg < 8; ++dg) {
        v8bf wf[4];
        #pragma unroll
        for (int cg = 0; cg < 4; ++cg) {
            const float* wp = W + (size_t)(dg * 16 + l15) * 128 + cg * 32 + quad * 8;
            float4 a = *(const float4*)wp;
            float4 c2 = *(const float4*)(wp + 4);
            union { __bf16 h[8]; v8bf v; } u;
            u.h[0] = (__bf16)a.x;  u.h[1] = (__bf16)a.y;  u.h[2] = (__bf16)a.z;  u.h[3] = (__bf16)a.w;
            u.h[4] = (__bf16)c2.x; u.h[5] = (__bf16)c2.y; u.h[6] = (__bf16)c2.z; u.h[7] = (__bf16)c2.w;
            wf[cg] = u.v;
        }
        v4f acc;
        #pragma unroll
        for (int r = 0; r < 4; ++r) acc[r] = bsh[dg * 16 + quad * 4 + r];
        #pragma unroll
        for (int cg = 0; cg < 4; ++cg)
            acc = MFMA16(wf[cg], xf[cg], acc, 0, 0, 0);

        const int tok = t0 + wave * 16 + l15;       // token within batch
        const int d0 = dg * 16 + quad * 4;          // 4 consecutive channels
        const unsigned u32 = pk4(acc[0], acc[1], acc[2], acc[3]);  // e4m3 RNE

        if (job <= 1) {
            // token-frag store: 4 consecutive d -> one u32
            // flane = ((d0>>3)&3)*16 + (tok&15)
            const size_t chunk = (job == 0)
                ? ((size_t)(b * 256 + (tok >> 4)) * 2 + (d0 >> 6))
                : ((size_t)(b * 32 + (tok >> 5)) * 4 + ((tok >> 4) & 1) * 2 + (d0 >> 6));
            unsigned char* Out = (job == 0) ? Qfr : Kfr;
            const size_t off = chunk * 1024
                             + (((d0 >> 3) & 3) * 16 + (tok & 15)) * 16
                             + ((d0 >> 5) & 1) * 8 + (d0 & 7);
            *(unsigned*)(Out + off) = u32;
        } else {
            // Vt scatter: element (ch=d, k=tok), byte stores
            #pragma unroll
            for (int r = 0; r < 4; ++r) {
                const int d = d0 + r;
                const size_t off = ((size_t)(b * 32 + (tok >> 5)) * 4 + (d >> 5)) * 1024
                                 + (((tok >> 3) & 3) * 16 + (d & 15)) * 16
                                 + ((d >> 4) & 1) * 8 + (tok & 7);
                Vfr[off] = (unsigned char)(u32 >> (8 * r));
            }
        }
    }
}

// split-chain S: two independent 4-deep chains (grp 0 / grp 1)
#define COMPUTE_S(S0, S1, KB)                                               \
    do {                                                                    \
        v4f a0, a1;                                                         \
        a0[0]=0.f;a0[1]=0.f;a0[2]=0.f;a0[3]=0.f;                            \
        a1[0]=0.f;a1[1]=0.f;a1[2]=0.f;a1[3]=0.f;                            \
        a0 = MFMA16F8(lo64(KB[0]), lo64(qv[0]), a0, 0, 0, 0);               \
        a1 = MFMA16F8(lo64(KB[2]), lo64(qv[0]), a1, 0, 0, 0);               \
        a0 = MFMA16F8(hi64(KB[0]), hi64(qv[0]), a0, 0, 0, 0);               \
        a1 = MFMA16F8(hi64(KB[2]), hi64(qv[0]), a1, 0, 0, 0);               \
        a0 = MFMA16F8(lo64(KB[1]), lo64(qv[1]), a0, 0, 0, 0);               \
        a1 = MFMA16F8(lo64(KB[3]), lo64(qv[1]), a1, 0, 0, 0);               \
        a0 = MFMA16F8(hi64(KB[1]), hi64(qv[1]), a0, 0, 0, 0);               \
        a1 = MFMA16F8(hi64(KB[3]), hi64(qv[1]), a1, 0, 0, 0);               \
        S0 = a0; S1 = a1;                                                   \
    } while (0)

// ---------------- Kernel 2: fp8 16-row split-K flash attn, pipelined --------
// 2048 blocks x 128 thr (8 blocks/CU -> 3 waves/SIMD at ~160 VGPR).
// Block: 16-q-row tile; wave w owns keys w*512..+511 (16 chunks of 32).
__global__ __launch_bounds__(128, 3) void attn(
    const float* __restrict__ x, const unsigned char* __restrict__ Qfr,
    const unsigned char* __restrict__ Kfr, const unsigned char* __restrict__ Vfr,
    float* __restrict__ out)
{
    __shared__ float Oacc[8 * 64 * 4];   // 8 KB: [cg][lane][reg]
    __shared__ float Lacc[2][16];

    const int tid = threadIdx.x;
    const int wave = tid >> 6, lane = tid & 63, l15 = lane & 15, quad = lane >> 4;
    const int b = blockIdx.x >> 8;
    const int qt = blockIdx.x & 255;     // 16-row q-tile within batch

    const unsigned char* Qc = Qfr + (size_t)(b * 256 + qt) * 2048;
    const unsigned char* Kc = Kfr + (size_t)(b * 32 + wave * 16) * 4096;
    const unsigned char* Vc = Vfr + (size_t)(b * 32 + wave * 16) * 4096;

    uint4 qv[2];
    #pragma unroll
    for (int p = 0; p < 2; ++p) qv[p] = *(const uint4*)(Qc + p * 1024 + lane * 16);

    v4f o[8];
    #pragma unroll
    for (int cg = 0; cg < 8; ++cg)
        #pragma unroll
        for (int r = 0; r < 4; ++r) o[cg][r] = 0.f;
    float l = 0.f;

    // double-buffered fragment preload (chunks 0 and 1)
    uint4 kb[2][4], vb[2][4];
    #pragma unroll
    for (int s = 0; s < 4; ++s) kb[0][s] = *(const uint4*)(Kc + s * 1024 + lane * 16);
    #pragma unroll
    for (int s = 0; s < 4; ++s) vb[0][s] = *(const uint4*)(Vc + s * 1024 + lane * 16);
    #pragma unroll
    for (int s = 0; s < 4; ++s) kb[1][s] = *(const uint4*)(Kc + 4096 + s * 1024 + lane * 16);
    #pragma unroll
    for (int s = 0; s < 4; ++s) vb[1][s] = *(const uint4*)(Vc + 4096 + s * 1024 + lane * 16);

    v4f S0, S1;
    COMPUTE_S(S0, S1, kb[0]);

    #pragma unroll
    for (int j = 0; j < 16; ++j) {
        const int cur = j & 1, nxt = (j + 1) & 1;

        // 1. prefetch K(j+2)
        if (j < 14) {
            #pragma unroll
            for (int s = 0; s < 4; ++s)
                kb[cur][s] = *(const uint4*)(Kc + (size_t)(j + 2) * 4096 + s * 1024 + lane * 16);
        }

        // 2. softmax on S(j): p = exp(S*scale - SMAX), per-lane partial l
        float p[8];
        #pragma unroll
        for (int r = 0; r < 4; ++r) {
            p[r]     = __expf(fmaf(S0[r], SCL, -SMAX));
            p[4 + r] = __expf(fmaf(S1[r], SCL, -SMAX));
        }
        #pragma unroll
        for (int r = 0; r < 8; ++r) l += p[r];

        // P: D-layout -> B-frag. Dest lane(quad) needs keys quad*8..+7, q=l15.
        // lo/hi sources: quadL = 2*(quad&1), quadH = quadL+1; grp = quad>>1.
        const unsigned u0 = pk4(p[0], p[1], p[2], p[3]);   // grp0 keys quad*4..+3
        const unsigned u1 = pk4(p[4], p[5], p[6], p[7]);   // grp1
        const int srcA = (2 * (quad & 1)) * 16 + l15;
        const int srcB = srcA + 16;
        const unsigned a0 = __shfl(u0, srcA);
        const unsigned a1 = __shfl(u1, srcA);
        const unsigned b0 = __shfl(u0, srcB);
        const unsigned b1 = __shfl(u1, srcB);
        const long long P64 = mk64((quad < 2) ? a0 : a1, (quad < 2) ? b0 : b1);

        // 3. S(j+1) — independent of PV(j)
        v4f T0 = S0, T1 = S1;
        if (j < 15) COMPUTE_S(T0, T1, kb[nxt]);

        // 4. PV(j): o[ch-group] += Vt . P   (8 independent MFMAs)
        #pragma unroll
        for (int cp = 0; cp < 4; ++cp) {
            o[2 * cp]     = MFMA16F8(lo64(vb[cur][cp]), P64, o[2 * cp], 0, 0, 0);
            o[2 * cp + 1] = MFMA16F8(hi64(vb[cur][cp]), P64, o[2 * cp + 1], 0, 0, 0);
        }

        // 5. prefetch V(j+2)
        if (j < 14) {
            #pragma unroll
            for (int s = 0; s < 4; ++s)
                vb[cur][s] = *(const uint4*)(Vc + (size_t)(j + 2) * 4096 + s * 1024 + lane * 16);
        }

        S0 = T0; S1 = T1;
    }

    // ---- row-sum reduce across quads (q = l15 column sum) ----
    l += __shfl_xor(l, 16);
    l += __shfl_xor(l, 32);
    if (lane < 16) Lacc[wave][lane] = l;

    // ---- split-K merge through LDS ----
    if (wave == 0) {
        #pragma unroll
        for (int cg = 0; cg < 8; ++cg)
            *(v4f*)(Oacc + cg * 256 + lane * 4) = o[cg];
    }
    __syncthreads();
    if (wave == 1) {
        #pragma unroll
        for (int cg = 0; cg < 8; ++cg) {
            v4f t = *(const v4f*)(Oacc + cg * 256 + lane * 4);
            #pragma unroll
            for (int r = 0; r < 4; ++r) t[r] += o[cg][r];
            *(v4f*)(Oacc + cg * 256 + lane * 4) = t;
        }
    }
    __syncthreads();

    const float linv = 1.0f / (Lacc[0][l15] + Lacc[1][l15]);

    // ---- epilogue: wave w stores cg = w*4..w*4+3; out = x + O/l ----
    #pragma unroll
    for (int cgl = 0; cgl < 4; ++cgl) {
        const int cg = wave * 4 + cgl;
        const v4f od = *(const v4f*)(Oacc + cg * 256 + lane * 4);
        #pragma unroll
        for (int r = 0; r < 4; ++r) {
            const int ch = cg * 16 + quad * 4 + r;
            const size_t gi = (size_t)(b * 128 + ch) * NN + qt * 16 + l15;
            out[gi] = x[gi] + od[r] * linv;
        }
    }
}

extern "C" void kernel_launch(void* const* d_in, const int* in_sizes, int n_in,
                              void* d_out, int out_size, void* d_ws, size_t ws_size,
                              hipStream_t stream) {
    const float* x  = (const float*)d_in[0];
    const float* y  = (const float*)d_in[1];
    const float* Wq = (const float*)d_in[2];
    const float* bq = (const float*)d_in[3];
    const float* Wk = (const float*)d_in[4];
    const float* bk = (const float*)d_in[5];
    const float* Wv = (const float*)d_in[6];
    const float* bv = (const float*)d_in[7];
    float* out = (float*)d_out;

    unsigned char* Qfr = (unsigned char*)d_ws;          // 4 MB
    unsigned char* Kfr = Qfr + (size_t)BB * NN * 128;   // 1 MB
    unsigned char* Vfr = Kfr + (size_t)BB * MMK * 128;  // 1 MB

    proj<<<768, 256, 0, stream>>>(x, y, Wq, bq, Wk, bk, Wv, bv, Qfr, Kfr, Vfr);
    attn<<<BB * (NN / 16), 128, 0, stream>>>(x, Qfr, Kfr, Vfr, out);
}